// Round 3
// baseline (513.249 us; speedup 1.0000x reference)
//
#include <hip/hip_runtime.h>
#include <hip/hip_bf16.h>

// Problem constants
#define BB 8
#define NN 128
#define CC 256
#define HFD 160
#define WFD 160
#define SS 7
#define REGION_OUT_ELEMS (8*128*256*49)   // 12,845,056
#define NTOT (BB*NN*49)                   // 50,176 = 784 * 64

typedef short short8 __attribute__((ext_vector_type(8)));
typedef float f32x4  __attribute__((ext_vector_type(4)));

// ---------------------------------------------------------------------------
// K0: convert proj_w [o][c] fp32 -> bf16 (row-major, A-operand friendly).
// ---------------------------------------------------------------------------
__global__ __launch_bounds__(256) void k0_convert_w(const float* __restrict__ W,
                                                    __hip_bfloat16* __restrict__ Wb) {
    int o = blockIdx.x;
    int c = threadIdx.x;
    Wb[o * CC + c] = __float2bfloat16(W[o * CC + c]);
}

// ---------------------------------------------------------------------------
// K1: column cumsum over h in NATIVE layout fm[b][c][h][w].
// One thread per (b,c,w) column: 327,680 threads = 20 waves/CU, no LDS,
// lanes = consecutive w -> coalesced 256B/wave per h-step.
// ---------------------------------------------------------------------------
__global__ __launch_bounds__(256) void k1_colsum(const float* __restrict__ fm,
                                                 float* __restrict__ C1) {
    int g  = blockIdx.x * 256 + threadIdx.x;     // 0 .. 327,679
    int bc = g / WFD;                            // (b*256 + c)
    int w  = g - bc * WFD;
    size_t base = (size_t)bc * (HFD * WFD) + w;
    float s = 0.f;
    #pragma unroll 8
    for (int h = 0; h < HFD; ++h) {
        s += fm[base + (size_t)h * WFD];
        C1[base + (size_t)h * WFD] = s;
    }
}

// ---------------------------------------------------------------------------
// K2: row cumsum over w + transpose to c-fastest.
//   in : C1[b][c][h][w]  (column-summed, w fastest)
//   out: I[b][h][w][c]   (c fastest) = full 2D inclusive integral image
// One WG per (b, h, c-quarter of 64 channels). LDS tile 64x161
// (161 == 1 mod 32: transpose-phase column reads are 2-way = free).
// ---------------------------------------------------------------------------
__global__ __launch_bounds__(256) void k2_rowsum_transpose(const float* __restrict__ C1,
                                                           float* __restrict__ I) {
    int bid = blockIdx.x;            // ((b*160)+h)*4 + cq
    int cq  = bid & 3;
    int bh  = bid >> 2;
    int h   = bh % HFD;
    int b   = bh / HFD;
    int c0  = cq * 64;
    int t   = threadIdx.x;

    __shared__ float tile[64][161];
    __shared__ float segsum[64][5];

    // load: 2560 float4 (64 channels x 160 w), coalesced
    #pragma unroll
    for (int it = 0; it < 10; ++it) {
        int vid = it * 256 + t;              // 0..2559
        int c_l = vid / 40;
        int wq  = vid - c_l * 40;            // float4 index within row
        float4 v = *(const float4*)(C1 + (((size_t)(b * CC + c0 + c_l)) * HFD + h) * WFD + wq * 4);
        tile[c_l][wq * 4 + 0] = v.x;
        tile[c_l][wq * 4 + 1] = v.y;
        tile[c_l][wq * 4 + 2] = v.z;
        tile[c_l][wq * 4 + 3] = v.w;
    }
    __syncthreads();

    // 4-segment parallel row scan (seg = 40 elements)
    int seg = t >> 6;        // 0..3
    int row = t & 63;        // 0..63
    {
        float s = 0.f;
        int w0 = seg * 40;
        #pragma unroll 8
        for (int k = 0; k < 40; ++k) {
            s += tile[row][w0 + k];
            tile[row][w0 + k] = s;
        }
        segsum[row][seg] = s;
    }
    __syncthreads();
    if (t < 64) {
        float a0 = segsum[t][0];
        float a1 = a0 + segsum[t][1];
        float a2 = a1 + segsum[t][2];
        segsum[t][1] = a0;
        segsum[t][2] = a1;
        segsum[t][3] = a2;
    }
    __syncthreads();
    if (seg > 0) {
        float off = segsum[row][seg];
        int w0 = seg * 40;
        #pragma unroll 8
        for (int k = 0; k < 40; ++k) tile[row][w0 + k] += off;
    }
    __syncthreads();

    // write transposed: I[b][h][w][c0 + 4*cg .. +3], float4 stores, coalesced in c
    size_t obase = (((size_t)b * HFD + h) * WFD) * CC + c0;
    #pragma unroll
    for (int it = 0; it < 10; ++it) {
        int vid = it * 256 + t;
        int w   = vid >> 4;        // 0..159
        int cg  = vid & 15;        // c = 4*cg
        float4 o;
        o.x = tile[cg * 4 + 0][w];
        o.y = tile[cg * 4 + 1][w];
        o.z = tile[cg * 4 + 2][w];
        o.w = tile[cg * 4 + 3][w];
        *(float4*)(I + obase + (size_t)w * CC + cg * 4) = o;
    }
}

// ---------------------------------------------------------------------------
// K3: per-(b,n): gather 49 box means from integral image, convert bf16,
// store P[bn*49 + cell][c]. No heavy LDS, no MFMA -> high occupancy; the
// 196 independent corner loads per thread hide L2/L3 latency.
// Also writes area_ratios.
// ---------------------------------------------------------------------------
__global__ __launch_bounds__(256) void k3_gather(
        const float* __restrict__ I, const float* __restrict__ bboxes,
        const int* __restrict__ ih_p, const int* __restrict__ iw_p,
        __hip_bfloat16* __restrict__ P, float* __restrict__ out) {
    int bn = blockIdx.x;         // b*128 + n
    int b  = bn >> 7;
    int t  = threadIdx.x;        // = channel c

    float bx1 = bboxes[bn * 4 + 0];
    float by1 = bboxes[bn * 4 + 1];
    float bx2 = bboxes[bn * 4 + 2];
    float by2 = bboxes[bn * 4 + 3];
    float sx = (float)WFD / (float)iw_p[0];
    float sy = (float)HFD / (float)ih_p[0];

    int x1 = min(max((int)floorf(bx1 * sx), 0), WFD - 1);
    int y1 = min(max((int)floorf(by1 * sy), 0), HFD - 1);
    int x2 = min(max((int)floorf(bx2 * sx), x1 + 1), WFD);
    int y2 = min(max((int)floorf(by2 * sy), y1 + 1), HFD);
    int Lx = x2 - x1, Ly = y2 - y1;

    int rs[SS], re[SS], cs[SS], ce[SS];
    #pragma unroll
    for (int i = 0; i < SS; ++i) {
        rs[i] = y1 + (i * Ly) / SS;
        re[i] = y1 + ((i + 1) * Ly + SS - 1) / SS;
        cs[i] = x1 + (i * Lx) / SS;
        ce[i] = x1 + ((i + 1) * Lx + SS - 1) / SS;
    }

    const int c = t;
    const size_t Ib = (size_t)b * HFD * WFD * CC;
    size_t pbase = (size_t)bn * 49 * CC + c;
    #pragma unroll
    for (int i = 0; i < SS; ++i) {
        int r0 = rs[i] - 1, r1 = re[i] - 1;
        float rh = (float)(re[i] - rs[i]);
        #pragma unroll
        for (int j = 0; j < SS; ++j) {
            int c0 = cs[j] - 1, c1 = ce[j] - 1;
            float br = I[Ib + ((size_t)(r1 * WFD + c1)) * CC + c];
            float tr = (r0 >= 0) ? I[Ib + ((size_t)(r0 * WFD + c1)) * CC + c] : 0.f;
            float bl = (c0 >= 0) ? I[Ib + ((size_t)(r1 * WFD + c0)) * CC + c] : 0.f;
            float tl = (r0 >= 0 && c0 >= 0) ? I[Ib + ((size_t)(r0 * WFD + c0)) * CC + c] : 0.f;
            float cnt = rh * (float)(ce[j] - cs[j]);
            P[pbase + (size_t)(i * SS + j) * CC] = __float2bfloat16((br - tr - bl + tl) / cnt);
        }
    }

    if (t == 0) {
        out[REGION_OUT_ELEMS + bn] = (bx2 - bx1) * (by2 - by1);
    }
}

// ---------------------------------------------------------------------------
// K4: GEMM out[bn][o][cell] = sum_c Wb[o][c] * P[bn*49+cell][c] + bias[o].
// M=256 (o), N=50176 (bn*49+cell, exactly 784 tiles of 64), K=256.
// P-tile staged to LDS (stride 264 bf16: b128 reads 2-way = free).
// Wave wv owns o in [64*wv, 64*wv+64).
// ---------------------------------------------------------------------------
#define PB_STRIDE 264

__global__ __launch_bounds__(256) void k4_gemm(
        const __hip_bfloat16* __restrict__ P, const __hip_bfloat16* __restrict__ Wb,
        const float* __restrict__ bias, float* __restrict__ out) {
    int n0 = blockIdx.x * 64;
    int t  = threadIdx.x;

    __shared__ __hip_bfloat16 Pb[64 * PB_STRIDE];   // 33 KB

    // stage P rows [n0, n0+64) x 256 c : 32 KB contiguous, short8 loads
    #pragma unroll
    for (int it = 0; it < 8; ++it) {
        int vid = it * 256 + t;         // 0..2047
        int row = vid >> 5;             // 0..63
        int cq  = vid & 31;             // 8-bf16 chunk
        short8 v = *(const short8*)((const short*)P + ((size_t)(n0 + row)) * CC + cq * 8);
        *(short8*)((short*)Pb + row * PB_STRIDE + cq * 8) = v;
    }
    __syncthreads();

    const int lane = t & 63;
    const int wv   = t >> 6;
    const int ln   = lane & 15;
    const int quad = lane >> 4;
    const int ob0  = wv * 64;

    f32x4 z = {0.f, 0.f, 0.f, 0.f};
    f32x4 acc[4][4];
    #pragma unroll
    for (int mt = 0; mt < 4; ++mt)
        #pragma unroll
        for (int nt = 0; nt < 4; ++nt) acc[mt][nt] = z;

    #pragma unroll
    for (int k0 = 0; k0 < CC; k0 += 32) {
        short8 a[4], bf[4];
        #pragma unroll
        for (int mt = 0; mt < 4; ++mt)
            a[mt] = *(const short8*)((const short*)Wb + (ob0 + mt * 16 + ln) * CC + k0 + quad * 8);
        #pragma unroll
        for (int nt = 0; nt < 4; ++nt)
            bf[nt] = *(const short8*)((const short*)Pb + (nt * 16 + ln) * PB_STRIDE + k0 + quad * 8);
        #pragma unroll
        for (int mt = 0; mt < 4; ++mt)
            #pragma unroll
            for (int nt = 0; nt < 4; ++nt)
                acc[mt][nt] = __builtin_amdgcn_mfma_f32_16x16x32_bf16(a[mt], bf[nt], acc[mt][nt], 0, 0, 0);
    }

    // epilogue: D layout col(cellg)=ln, row(o)=quad*4+reg
    #pragma unroll
    for (int mt = 0; mt < 4; ++mt) {
        f32x4 bv = *(const f32x4*)(bias + ob0 + mt * 16 + quad * 4);
        #pragma unroll
        for (int nt = 0; nt < 4; ++nt) {
            int cellg = n0 + nt * 16 + ln;
            int bn    = cellg / 49;
            int cell  = cellg - bn * 49;
            size_t base = (size_t)bn * (CC * 49) + (size_t)(ob0 + mt * 16 + quad * 4) * 49 + cell;
            #pragma unroll
            for (int reg = 0; reg < 4; ++reg) {
                out[base + (size_t)reg * 49] = acc[mt][nt][reg] + bv[reg];
            }
        }
    }
}

// ---------------------------------------------------------------------------
extern "C" void kernel_launch(void* const* d_in, const int* in_sizes, int n_in,
                              void* d_out, int out_size, void* d_ws, size_t ws_size,
                              hipStream_t stream) {
    const float* fm     = (const float*)d_in[0];
    const float* bboxes = (const float*)d_in[1];
    const float* W      = (const float*)d_in[2];
    const float* bias   = (const float*)d_in[3];
    const int*   ih     = (const int*)d_in[4];
    const int*   iw     = (const int*)d_in[5];
    float* out = (float*)d_out;

    const size_t FM_BYTES = (size_t)BB * CC * HFD * WFD * 4;   // 209,715,200
    char* ws = (char*)d_ws;
    __hip_bfloat16* Wb = (__hip_bfloat16*)ws;                  // 128 KB
    float* C1 = (float*)(ws + 131072);                         // 210 MB
    float* I  = (float*)(ws + 131072 + FM_BYTES);              // 210 MB
    __hip_bfloat16* P = (__hip_bfloat16*)(ws + 131072 + 2 * FM_BYTES);  // 25 MB

    k0_convert_w       <<<CC, 256, 0, stream>>>(W, Wb);
    k1_colsum          <<<(BB * CC * WFD) / 256, 256, 0, stream>>>(fm, C1);
    k2_rowsum_transpose<<<BB * HFD * 4, 256, 0, stream>>>(C1, I);
    k3_gather          <<<BB * NN, 256, 0, stream>>>(I, bboxes, ih, iw, P, out);
    k4_gemm            <<<NTOT / 64, 256, 0, stream>>>(P, Wb, bias, out);
}

// Round 4
// 479.839 us; speedup vs baseline: 1.0696x; 1.0696x over previous
//
#include <hip/hip_runtime.h>
#include <hip/hip_bf16.h>

// Problem constants
#define BB 8
#define NN 128
#define CC 256
#define HFD 160
#define WFD 160
#define SS 7
#define REGION_OUT_ELEMS (8*128*256*49)   // 12,845,056
#define NTOT (BB*NN*49)                   // 50,176 = 784 * 64

typedef short short8 __attribute__((ext_vector_type(8)));
typedef float f32x4  __attribute__((ext_vector_type(4)));

// ---------------------------------------------------------------------------
// K0: convert proj_w [o][c] fp32 -> bf16 (row-major, A-operand friendly).
// ---------------------------------------------------------------------------
__global__ __launch_bounds__(256) void k0_convert_w(const float* __restrict__ W,
                                                    __hip_bfloat16* __restrict__ Wb) {
    int o = blockIdx.x;
    int c = threadIdx.x;
    Wb[o * CC + c] = __float2bfloat16(W[o * CC + c]);
}

// ---------------------------------------------------------------------------
// K1: fused row-cumsum (over w) + transpose, reading fm directly.
//   in : fm[b][c][h][w]   (w fastest)
//   out: I[b][h][w][c]    (c fastest) -- row-summed only; K2 adds h-cumsum.
// One WG per (b, h, c-quarter of 64 channels). LDS tile 64x161
// (161 == 1 mod 32: transpose-phase column reads are 2-way = free).
// ---------------------------------------------------------------------------
__global__ __launch_bounds__(256) void k1_rowsum_transpose(const float* __restrict__ fm,
                                                           float* __restrict__ I) {
    int bid = blockIdx.x;            // ((b*160)+h)*4 + cq
    int cq  = bid & 3;
    int bh  = bid >> 2;
    int h   = bh % HFD;
    int b   = bh / HFD;
    int c0  = cq * 64;
    int t   = threadIdx.x;

    __shared__ float tile[64][161];
    __shared__ float segsum[64][5];

    // load: 2560 float4 (64 channels x 160 w), coalesced
    #pragma unroll
    for (int it = 0; it < 10; ++it) {
        int vid = it * 256 + t;              // 0..2559
        int c_l = vid / 40;
        int wq  = vid - c_l * 40;            // float4 index within row
        float4 v = *(const float4*)(fm + (((size_t)(b * CC + c0 + c_l)) * HFD + h) * WFD + wq * 4);
        tile[c_l][wq * 4 + 0] = v.x;
        tile[c_l][wq * 4 + 1] = v.y;
        tile[c_l][wq * 4 + 2] = v.z;
        tile[c_l][wq * 4 + 3] = v.w;
    }
    __syncthreads();

    // 4-segment parallel row scan (seg = 40 elements)
    int seg = t >> 6;        // 0..3
    int row = t & 63;        // 0..63
    {
        float s = 0.f;
        int w0 = seg * 40;
        #pragma unroll 8
        for (int k = 0; k < 40; ++k) {
            s += tile[row][w0 + k];
            tile[row][w0 + k] = s;
        }
        segsum[row][seg] = s;
    }
    __syncthreads();
    if (t < 64) {
        float a0 = segsum[t][0];
        float a1 = a0 + segsum[t][1];
        float a2 = a1 + segsum[t][2];
        segsum[t][1] = a0;
        segsum[t][2] = a1;
        segsum[t][3] = a2;
    }
    __syncthreads();
    if (seg > 0) {
        float off = segsum[row][seg];
        int w0 = seg * 40;
        #pragma unroll 8
        for (int k = 0; k < 40; ++k) tile[row][w0 + k] += off;
    }
    __syncthreads();

    // write transposed: I[b][h][w][c0 + 4*cg .. +3], float4 stores, coalesced in c
    size_t obase = (((size_t)b * HFD + h) * WFD) * CC + c0;
    #pragma unroll
    for (int it = 0; it < 10; ++it) {
        int vid = it * 256 + t;
        int w   = vid >> 4;        // 0..159
        int cg  = vid & 15;        // c = 4*cg
        float4 o;
        o.x = tile[cg * 4 + 0][w];
        o.y = tile[cg * 4 + 1][w];
        o.z = tile[cg * 4 + 2][w];
        o.w = tile[cg * 4 + 3][w];
        *(float4*)(I + obase + (size_t)w * CC + cg * 4) = o;
    }
}

// ---------------------------------------------------------------------------
// K2: in-place column cumsum over h in c-fastest layout.
// One 256-thread WG per (b,w); thread = one channel c (scalar RMW).
// 1280 blocks x 4 waves = 20 waves/CU (4x round-2's occupancy), 1KB
// contiguous per block per h-step.
// ---------------------------------------------------------------------------
__global__ __launch_bounds__(256) void k2_colsum(float* __restrict__ I) {
    int w = blockIdx.x % WFD;
    int b = blockIdx.x / WFD;
    int c = threadIdx.x;
    float* p = I + (((size_t)b * HFD) * WFD + w) * CC + c;    // h = 0
    const size_t stride = (size_t)WFD * CC;                   // per-h stride (floats)
    float s = 0.f;
    #pragma unroll 8
    for (int h = 0; h < HFD; ++h) {
        float v = p[(size_t)h * stride];
        s += v;
        p[(size_t)h * stride] = s;
    }
}

// ---------------------------------------------------------------------------
// K3: per-(b,n): gather 49 box means from integral image, convert bf16,
// store P[bn*49 + cell][c]. No heavy LDS, no MFMA -> high occupancy; the
// 196 independent corner loads per thread hide L2/L3 latency.
// Also writes area_ratios.
// ---------------------------------------------------------------------------
__global__ __launch_bounds__(256) void k3_gather(
        const float* __restrict__ I, const float* __restrict__ bboxes,
        const int* __restrict__ ih_p, const int* __restrict__ iw_p,
        __hip_bfloat16* __restrict__ P, float* __restrict__ out) {
    int bn = blockIdx.x;         // b*128 + n
    int b  = bn >> 7;
    int t  = threadIdx.x;        // = channel c

    float bx1 = bboxes[bn * 4 + 0];
    float by1 = bboxes[bn * 4 + 1];
    float bx2 = bboxes[bn * 4 + 2];
    float by2 = bboxes[bn * 4 + 3];
    float sx = (float)WFD / (float)iw_p[0];
    float sy = (float)HFD / (float)ih_p[0];

    int x1 = min(max((int)floorf(bx1 * sx), 0), WFD - 1);
    int y1 = min(max((int)floorf(by1 * sy), 0), HFD - 1);
    int x2 = min(max((int)floorf(bx2 * sx), x1 + 1), WFD);
    int y2 = min(max((int)floorf(by2 * sy), y1 + 1), HFD);
    int Lx = x2 - x1, Ly = y2 - y1;

    int rs[SS], re[SS], cs[SS], ce[SS];
    #pragma unroll
    for (int i = 0; i < SS; ++i) {
        rs[i] = y1 + (i * Ly) / SS;
        re[i] = y1 + ((i + 1) * Ly + SS - 1) / SS;
        cs[i] = x1 + (i * Lx) / SS;
        ce[i] = x1 + ((i + 1) * Lx + SS - 1) / SS;
    }

    const int c = t;
    const size_t Ib = (size_t)b * HFD * WFD * CC;
    size_t pbase = (size_t)bn * 49 * CC + c;
    #pragma unroll
    for (int i = 0; i < SS; ++i) {
        int r0 = rs[i] - 1, r1 = re[i] - 1;
        float rh = (float)(re[i] - rs[i]);
        #pragma unroll
        for (int j = 0; j < SS; ++j) {
            int c0 = cs[j] - 1, c1 = ce[j] - 1;
            float br = I[Ib + ((size_t)(r1 * WFD + c1)) * CC + c];
            float tr = (r0 >= 0) ? I[Ib + ((size_t)(r0 * WFD + c1)) * CC + c] : 0.f;
            float bl = (c0 >= 0) ? I[Ib + ((size_t)(r1 * WFD + c0)) * CC + c] : 0.f;
            float tl = (r0 >= 0 && c0 >= 0) ? I[Ib + ((size_t)(r0 * WFD + c0)) * CC + c] : 0.f;
            float cnt = rh * (float)(ce[j] - cs[j]);
            P[pbase + (size_t)(i * SS + j) * CC] = __float2bfloat16((br - tr - bl + tl) / cnt);
        }
    }

    if (t == 0) {
        out[REGION_OUT_ELEMS + bn] = (bx2 - bx1) * (by2 - by1);
    }
}

// ---------------------------------------------------------------------------
// K4: GEMM out[bn][o][cell] = sum_c Wb[o][c] * P[bn*49+cell][c] + bias[o].
// M=256 (o), N=50176 (bn*49+cell, exactly 784 tiles of 64), K=256.
// P-tile staged to LDS (stride 264 bf16: b128 reads 2-way = free).
// Wave wv owns o in [64*wv, 64*wv+64).
// ---------------------------------------------------------------------------
#define PB_STRIDE 264

__global__ __launch_bounds__(256) void k4_gemm(
        const __hip_bfloat16* __restrict__ P, const __hip_bfloat16* __restrict__ Wb,
        const float* __restrict__ bias, float* __restrict__ out) {
    int n0 = blockIdx.x * 64;
    int t  = threadIdx.x;

    __shared__ __hip_bfloat16 Pb[64 * PB_STRIDE];   // 33 KB

    // stage P rows [n0, n0+64) x 256 c : 32 KB contiguous, short8 loads
    #pragma unroll
    for (int it = 0; it < 8; ++it) {
        int vid = it * 256 + t;         // 0..2047
        int row = vid >> 5;             // 0..63
        int cq  = vid & 31;             // 8-bf16 chunk
        short8 v = *(const short8*)((const short*)P + ((size_t)(n0 + row)) * CC + cq * 8);
        *(short8*)((short*)Pb + row * PB_STRIDE + cq * 8) = v;
    }
    __syncthreads();

    const int lane = t & 63;
    const int wv   = t >> 6;
    const int ln   = lane & 15;
    const int quad = lane >> 4;
    const int ob0  = wv * 64;

    f32x4 z = {0.f, 0.f, 0.f, 0.f};
    f32x4 acc[4][4];
    #pragma unroll
    for (int mt = 0; mt < 4; ++mt)
        #pragma unroll
        for (int nt = 0; nt < 4; ++nt) acc[mt][nt] = z;

    #pragma unroll
    for (int k0 = 0; k0 < CC; k0 += 32) {
        short8 a[4], bf[4];
        #pragma unroll
        for (int mt = 0; mt < 4; ++mt)
            a[mt] = *(const short8*)((const short*)Wb + (ob0 + mt * 16 + ln) * CC + k0 + quad * 8);
        #pragma unroll
        for (int nt = 0; nt < 4; ++nt)
            bf[nt] = *(const short8*)((const short*)Pb + (nt * 16 + ln) * PB_STRIDE + k0 + quad * 8);
        #pragma unroll
        for (int mt = 0; mt < 4; ++mt)
            #pragma unroll
            for (int nt = 0; nt < 4; ++nt)
                acc[mt][nt] = __builtin_amdgcn_mfma_f32_16x16x32_bf16(a[mt], bf[nt], acc[mt][nt], 0, 0, 0);
    }

    // epilogue: D layout col(cellg)=ln, row(o)=quad*4+reg
    #pragma unroll
    for (int mt = 0; mt < 4; ++mt) {
        f32x4 bv = *(const f32x4*)(bias + ob0 + mt * 16 + quad * 4);
        #pragma unroll
        for (int nt = 0; nt < 4; ++nt) {
            int cellg = n0 + nt * 16 + ln;
            int bn    = cellg / 49;
            int cell  = cellg - bn * 49;
            size_t base = (size_t)bn * (CC * 49) + (size_t)(ob0 + mt * 16 + quad * 4) * 49 + cell;
            #pragma unroll
            for (int reg = 0; reg < 4; ++reg) {
                out[base + (size_t)reg * 49] = acc[mt][nt][reg] + bv[reg];
            }
        }
    }
}

// ---------------------------------------------------------------------------
extern "C" void kernel_launch(void* const* d_in, const int* in_sizes, int n_in,
                              void* d_out, int out_size, void* d_ws, size_t ws_size,
                              hipStream_t stream) {
    const float* fm     = (const float*)d_in[0];
    const float* bboxes = (const float*)d_in[1];
    const float* W      = (const float*)d_in[2];
    const float* bias   = (const float*)d_in[3];
    const int*   ih     = (const int*)d_in[4];
    const int*   iw     = (const int*)d_in[5];
    float* out = (float*)d_out;

    const size_t FM_BYTES = (size_t)BB * CC * HFD * WFD * 4;   // 209,715,200
    char* ws = (char*)d_ws;
    __hip_bfloat16* Wb = (__hip_bfloat16*)ws;                  // 128 KB
    float* I  = (float*)(ws + 131072);                         // 210 MB
    __hip_bfloat16* P = (__hip_bfloat16*)(ws + 131072 + FM_BYTES);  // 25 MB

    k0_convert_w       <<<CC, 256, 0, stream>>>(W, Wb);
    k1_rowsum_transpose<<<BB * HFD * 4, 256, 0, stream>>>(fm, I);
    k2_colsum          <<<BB * WFD, 256, 0, stream>>>(I);
    k3_gather          <<<BB * NN, 256, 0, stream>>>(I, bboxes, ih, iw, P, out);
    k4_gemm            <<<NTOT / 64, 256, 0, stream>>>(P, Wb, bias, out);
}